// Round 3
// baseline (175.669 us; speedup 1.0000x reference)
//
#include <hip/hip_runtime.h>

// ANOVA kernel order 3:  out[b] = sum_e e3(x[b, :, e])
// x: (8192, 64, 64) fp32, row-major, e innermost.
//
// R7 = R6 (non-temporal loads; total 174.7 us, -10 vs R4) + occupancy push.
// R6 post-mortem: kernel ~12 us => ~11 TB/s read, ABOVE HBM peak => x
// (134.2 MB) is Infinity-Cache-resident across bench iterations; nt loads
// stopped L2 allocate/evict thrash on single-use lines and the stream is
// served from L3. Regime changed from HBM-BW-bound to (plausibly)
// L3-latency-bound, so the TLP axis is worth re-testing (R5's null was
// measured in the old regime):
//   - __launch_bounds__(256, 8): <=64 VGPR -> 8 waves/SIMD (32/CU).
//   - Hand 2x4 double-buffered load pipeline (max 8 live float4 = 32 VGPR
//     data) so the cap doesn't spill; FP order identical to R4/R6.
// Predict: kernel ~12 -> 8-9 us (total ~171) if latency-bound; neutral =>
// L3 service ceiling reached -> roofline.

constexpr int BATCH = 8192;

using f32x4 = __attribute__((ext_vector_type(4))) float;

__device__ inline f32x4 shfl_xor4(f32x4 v, int d) {
    f32x4 r;
    r.x = __shfl_xor(v.x, d);
    r.y = __shfl_xor(v.y, d);
    r.z = __shfl_xor(v.z, d);
    r.w = __shfl_xor(v.w, d);
    return r;
}

// ESP DP step; order matters: s3 uses old s2, s2 uses old s1.
#define ESP_STEP(v)                                                            \
    s3.x = fmaf(s2.x, (v).x, s3.x); s2.x = fmaf(s1.x, (v).x, s2.x); s1.x += (v).x; \
    s3.y = fmaf(s2.y, (v).y, s3.y); s2.y = fmaf(s1.y, (v).y, s2.y); s1.y += (v).y; \
    s3.z = fmaf(s2.z, (v).z, s3.z); s2.z = fmaf(s1.z, (v).z, s2.z); s1.z += (v).z; \
    s3.w = fmaf(s2.w, (v).w, s3.w); s2.w = fmaf(s1.w, (v).w, s2.w); s1.w += (v).w;

__global__ __launch_bounds__(256, 8) void anova3_kernel(const float* __restrict__ x,
                                                        float* __restrict__ out) {
    const int tid  = blockIdx.x * 256 + threadIdx.x;
    const int lane = threadIdx.x & 63;
    const int b    = tid >> 6;        // one wave per batch row

    // Row = 1024 float4 units. Load i covers units [i*64, (i+1)*64): 1 KB contiguous.
    const f32x4* xp = reinterpret_cast<const f32x4*>(x)
                    + (size_t)b * 1024 + lane;

    f32x4 s1 = {0.f, 0.f, 0.f, 0.f};
    f32x4 s2 = s1, s3 = s1;

    // Two 4-load batches in flight; process i = 0..15 in order (identical
    // FP order to R4/R6).
    f32x4 a0 = __builtin_nontemporal_load(xp + 0 * 64);
    f32x4 a1 = __builtin_nontemporal_load(xp + 1 * 64);
    f32x4 a2 = __builtin_nontemporal_load(xp + 2 * 64);
    f32x4 a3 = __builtin_nontemporal_load(xp + 3 * 64);
    f32x4 b0 = __builtin_nontemporal_load(xp + 4 * 64);
    f32x4 b1 = __builtin_nontemporal_load(xp + 5 * 64);
    f32x4 b2 = __builtin_nontemporal_load(xp + 6 * 64);
    f32x4 b3 = __builtin_nontemporal_load(xp + 7 * 64);

    ESP_STEP(a0) ESP_STEP(a1) ESP_STEP(a2) ESP_STEP(a3)      // i = 0..3
    a0 = __builtin_nontemporal_load(xp + 8 * 64);
    a1 = __builtin_nontemporal_load(xp + 9 * 64);
    a2 = __builtin_nontemporal_load(xp + 10 * 64);
    a3 = __builtin_nontemporal_load(xp + 11 * 64);

    ESP_STEP(b0) ESP_STEP(b1) ESP_STEP(b2) ESP_STEP(b3)      // i = 4..7
    b0 = __builtin_nontemporal_load(xp + 12 * 64);
    b1 = __builtin_nontemporal_load(xp + 13 * 64);
    b2 = __builtin_nontemporal_load(xp + 14 * 64);
    b3 = __builtin_nontemporal_load(xp + 15 * 64);

    ESP_STEP(a0) ESP_STEP(a1) ESP_STEP(a2) ESP_STEP(a3)      // i = 8..11
    ESP_STEP(b0) ESP_STEP(b1) ESP_STEP(b2) ESP_STEP(b3)      // i = 12..15

    // Merge the 4 disjoint field subsets across h = lane>>4.
#pragma unroll
    for (int d = 16; d <= 32; d <<= 1) {
        f32x4 o1 = shfl_xor4(s1, d);
        f32x4 o2 = shfl_xor4(s2, d);
        f32x4 o3 = shfl_xor4(s3, d);
        s3.x += o3.x + s2.x * o1.x + s1.x * o2.x;
        s3.y += o3.y + s2.y * o1.y + s1.y * o2.y;
        s3.z += o3.z + s2.z * o1.z + s1.z * o2.z;
        s3.w += o3.w + s2.w * o1.w + s1.w * o2.w;
        s2.x += o2.x + s1.x * o1.x;
        s2.y += o2.y + s1.y * o1.y;
        s2.z += o2.z + s1.z * o1.z;
        s2.w += o2.w + s1.w * o1.w;
        s1.x += o1.x; s1.y += o1.y; s1.z += o1.z; s1.w += o1.w;
    }

    // Sum e3 over components and over the 16 g-groups (lane bits 0..3).
    float r = (s3.x + s3.y) + (s3.z + s3.w);
    r += __shfl_xor(r, 1);
    r += __shfl_xor(r, 2);
    r += __shfl_xor(r, 4);
    r += __shfl_xor(r, 8);

    if (lane == 0) out[b] = r;
}

extern "C" void kernel_launch(void* const* d_in, const int* in_sizes, int n_in,
                              void* d_out, int out_size, void* d_ws, size_t ws_size,
                              hipStream_t stream) {
    const float* x = (const float*)d_in[0];
    float* out = (float*)d_out;
    const int total_threads = BATCH * 64;   // one wave per row
    dim3 grid(total_threads / 256);         // 2048 blocks
    anova3_kernel<<<grid, dim3(256), 0, stream>>>(x, out);
}